// Round 15
// baseline (333.682 us; speedup 1.0000x reference)
//
#include <hip/hip_runtime.h>

#define SCAP_EGO 8192   // staging cap per 256-node bin (mean 6144)
#define SCAP_E   4096   // mean 3072

typedef unsigned short ushort_t;
typedef unsigned int uint_t;
typedef __attribute__((ext_vector_type(8))) short bf16x8;
typedef __attribute__((ext_vector_type(4))) float f32x4;

__device__ inline float lo16(uint_t u) { return __uint_as_float(u << 16); }
__device__ inline float hi16(uint_t u) { return __uint_as_float(u & 0xFFFF0000u); }
__device__ inline ushort_t f2bf(float f) {
    uint_t i = __float_as_uint(f);
    return (ushort_t)((i + 0x7FFFu + ((i >> 16) & 1u)) >> 16);
}
__device__ inline uint_t pack2(float a, float b) {
    return (uint_t)f2bf(a) | ((uint_t)f2bf(b) << 16);
}
union U8 { uint4 u; bf16x8 v; };

// ======== prep: x fp32->bf16, weights fp32->bf16 W^T, zero cursors ========
__global__ __launch_bounds__(256) void prep(
    const float* __restrict__ x, ushort_t* __restrict__ xb, int n8,
    const float* __restrict__ W0, const float* __restrict__ W1,
    const float* __restrict__ W2, const float* __restrict__ W3,
    ushort_t* __restrict__ T0, ushort_t* __restrict__ T1,
    ushort_t* __restrict__ T2, ushort_t* __restrict__ T3,
    int* __restrict__ z)
{
    int i = blockIdx.x * 256 + threadIdx.x;
    if (i < 128) ((int4*)z)[i] = make_int4(0, 0, 0, 0);
    if (i < n8) {
        const float4* p = (const float4*)(x + (size_t)i * 8);
        float4 a = p[0], b = p[1];
        uint4 o;
        o.x = pack2(a.x, a.y); o.y = pack2(a.z, a.w);
        o.z = pack2(b.x, b.y); o.w = pack2(b.z, b.w);
        *(uint4*)(xb + (size_t)i * 8) = o;
    }
    if (i < 49152) {
        int mi = i >> 14;
        int r = i & 16383;
        int n = r >> 7, k = r & 127;
        const float* W = mi == 0 ? W0 : (mi == 1 ? W1 : W2);
        ushort_t* T = mi == 0 ? T0 : (mi == 1 ? T1 : T2);
        T[n * 128 + k] = f2bf(W[k * 128 + n]);
    } else if (i < 49152 + 6144) {
        int r = i - 49152;
        int n = r >> 7, k = r & 127;
        T3[n * 128 + k] = (n < 47) ? f2bf(W3[k * 47 + n]) : (ushort_t)0;
    }
}

// ======== merged phase A: bin edges of BOTH graphs (block-range branch) ====
__global__ __launch_bounds__(256) void bin_edges2(
    const int* __restrict__ d1, const int* __restrict__ s1, int n1, int nb1,
    int* __restrict__ cur1, int2* __restrict__ st1, int scap1,
    const int* __restrict__ d2, const int* __restrict__ s2, int n2,
    int* __restrict__ cur2, int2* __restrict__ st2, int scap2)
{
    const int* dst; const int* src; int nE, scap; int* bincur; int2* stage; int bid;
    if (blockIdx.x < (uint_t)nb1) {
        dst = d1; src = s1; nE = n1; scap = scap1; bincur = cur1; stage = st1;
        bid = blockIdx.x;
    } else {
        dst = d2; src = s2; nE = n2; scap = scap2; bincur = cur2; stage = st2;
        bid = blockIdx.x - nb1;
    }
    __shared__ int bcnt[256];
    __shared__ int gbase[256];
    int t = threadIdx.x;
    bcnt[t] = 0;
    __syncthreads();
    int base = bid * 4096;
    int d[16], s[16], l[16];
#pragma unroll
    for (int i = 0; i < 16; i++) {
        int e = base + t + i * 256;
        if (e < nE) {
            d[i] = dst[e]; s[i] = src[e];
            l[i] = atomicAdd(&bcnt[d[i] >> 8], 1);
        } else d[i] = -1;
    }
    __syncthreads();
    if (bcnt[t]) gbase[t] = atomicAdd(&bincur[t], bcnt[t]);
    __syncthreads();
#pragma unroll
    for (int i = 0; i < 16; i++) {
        if (d[i] >= 0) {
            int b = d[i] >> 8;
            int slot = gbase[b] + l[i];
            if (slot < scap) stage[(size_t)b * scap + slot] = make_int2(d[i], s[i]);
        }
    }
}

// ======== merged phase B: counting sort -> packed CSR + degree-rank remap ====
// blocks [0,NB) = graph1 bins, [NB,2NB) = graph2. Bitonic-sorts the bin's 256
// nodes by degree (ascending) into remap so co-waved nodes have equal work.
__global__ __launch_bounds__(256) void build_csr2(
    const int* __restrict__ cur1, const int2* __restrict__ st1, int scap1,
    int* __restrict__ cnt1, int* __restrict__ rp1, int* __restrict__ pk1,
    int* __restrict__ remap1,
    const int* __restrict__ cur2, const int2* __restrict__ st2, int scap2,
    int* __restrict__ cnt2, int* __restrict__ rp2, int* __restrict__ pk2,
    int* __restrict__ remap2, int NB)
{
    const int* bincur; const int2* stage; int scap;
    int* cnt; int* rowptr; int* packed; int* remap; int b;
    if (blockIdx.x < (uint_t)NB) {
        bincur = cur1; stage = st1; scap = scap1;
        cnt = cnt1; rowptr = rp1; packed = pk1; remap = remap1; b = blockIdx.x;
    } else {
        bincur = cur2; stage = st2; scap = scap2;
        cnt = cnt2; rowptr = rp2; packed = pk2; remap = remap2; b = blockIdx.x - NB;
    }
    __shared__ int sc[256];
    __shared__ int wcur[256];
    __shared__ uint_t key[256];
    int t = threadIdx.x;
    int m = bincur[b]; if (m > scap) m = scap;
    const int2* st = stage + (size_t)b * scap;
    sc[t] = 0;
    __syncthreads();
    for (int e = t; e < m; e += 256) atomicAdd(&sc[st[e].x & 255], 1);
    __syncthreads();
    int v = sc[t];
    __syncthreads();
    sc[t] = v;
    key[t] = ((uint_t)v << 8) | (uint_t)t;       // degree-major sort key
    __syncthreads();
    for (int off = 1; off < 256; off <<= 1) {    // inclusive scan of counts
        int y = (t >= off) ? sc[t - off] : 0;
        __syncthreads();
        sc[t] += y;
        __syncthreads();
    }
    int excl = sc[t] - v;
    cnt[b * 256 + t] = v;
    rowptr[b * 256 + t] = b * scap + excl;
    wcur[t] = excl;
    // bitonic sort (ascending) of key[]
    for (int k = 2; k <= 256; k <<= 1) {
        for (int j = k >> 1; j > 0; j >>= 1) {
            __syncthreads();
            int ixj = t ^ j;
            if (ixj > t) {
                uint_t a = key[t], c = key[ixj];
                bool dir = ((t & k) == 0);       // ascending block
                if ((a > c) == dir) { key[t] = c; key[ixj] = a; }
            }
        }
    }
    __syncthreads();
    remap[b * 256 + t] = b * 256 + (int)(key[t] & 255u);
    int* pk = packed + (size_t)b * scap;
    for (int e = t; e < m; e += 256) {
        int2 p = st[e];
        int slot = atomicAdd(&wcur[p.x & 255], 1);
        pk[slot] = p.y;
    }
}

// ======== gather-sum: 16-lane group per node (via remap), unroll x8 ========
__global__ __launch_bounds__(256) void gather_bf(
    const ushort_t* __restrict__ x, const int* __restrict__ cnt,
    const int* __restrict__ rowptr, const int* __restrict__ packed,
    const int* __restrict__ remap, ushort_t* __restrict__ outb,
    int nNodes, float scale, int selfAdd)
{
    int g = threadIdx.x >> 4, lane = threadIdx.x & 15;
    int n = remap[blockIdx.x * 16 + g];
    if (n >= nNodes) return;
    int len = cnt[n];
    const int* row = packed + rowptr[n];
    const ushort_t* base = x + lane * 8;
    float a[8];
#pragma unroll
    for (int m = 0; m < 8; m++) a[m] = 0.f;
    int e = 0;
    for (; e + 7 < len; e += 8) {
        uint4 w0 = *(const uint4*)(base + (size_t)row[e + 0] * 128);
        uint4 w1 = *(const uint4*)(base + (size_t)row[e + 1] * 128);
        uint4 w2 = *(const uint4*)(base + (size_t)row[e + 2] * 128);
        uint4 w3 = *(const uint4*)(base + (size_t)row[e + 3] * 128);
        uint4 w4 = *(const uint4*)(base + (size_t)row[e + 4] * 128);
        uint4 w5 = *(const uint4*)(base + (size_t)row[e + 5] * 128);
        uint4 w6 = *(const uint4*)(base + (size_t)row[e + 6] * 128);
        uint4 w7 = *(const uint4*)(base + (size_t)row[e + 7] * 128);
        a[0] += (lo16(w0.x) + lo16(w1.x)) + (lo16(w2.x) + lo16(w3.x))
              + (lo16(w4.x) + lo16(w5.x)) + (lo16(w6.x) + lo16(w7.x));
        a[1] += (hi16(w0.x) + hi16(w1.x)) + (hi16(w2.x) + hi16(w3.x))
              + (hi16(w4.x) + hi16(w5.x)) + (hi16(w6.x) + hi16(w7.x));
        a[2] += (lo16(w0.y) + lo16(w1.y)) + (lo16(w2.y) + lo16(w3.y))
              + (lo16(w4.y) + lo16(w5.y)) + (lo16(w6.y) + lo16(w7.y));
        a[3] += (hi16(w0.y) + hi16(w1.y)) + (hi16(w2.y) + hi16(w3.y))
              + (hi16(w4.y) + hi16(w5.y)) + (hi16(w6.y) + hi16(w7.y));
        a[4] += (lo16(w0.z) + lo16(w1.z)) + (lo16(w2.z) + lo16(w3.z))
              + (lo16(w4.z) + lo16(w5.z)) + (lo16(w6.z) + lo16(w7.z));
        a[5] += (hi16(w0.z) + hi16(w1.z)) + (hi16(w2.z) + hi16(w3.z))
              + (hi16(w4.z) + hi16(w5.z)) + (hi16(w6.z) + hi16(w7.z));
        a[6] += (lo16(w0.w) + lo16(w1.w)) + (lo16(w2.w) + lo16(w3.w))
              + (lo16(w4.w) + lo16(w5.w)) + (lo16(w6.w) + lo16(w7.w));
        a[7] += (hi16(w0.w) + hi16(w1.w)) + (hi16(w2.w) + hi16(w3.w))
              + (hi16(w4.w) + hi16(w5.w)) + (hi16(w6.w) + hi16(w7.w));
    }
    for (; e + 3 < len; e += 4) {
        uint4 w0 = *(const uint4*)(base + (size_t)row[e + 0] * 128);
        uint4 w1 = *(const uint4*)(base + (size_t)row[e + 1] * 128);
        uint4 w2 = *(const uint4*)(base + (size_t)row[e + 2] * 128);
        uint4 w3 = *(const uint4*)(base + (size_t)row[e + 3] * 128);
        a[0] += lo16(w0.x) + lo16(w1.x) + lo16(w2.x) + lo16(w3.x);
        a[1] += hi16(w0.x) + hi16(w1.x) + hi16(w2.x) + hi16(w3.x);
        a[2] += lo16(w0.y) + lo16(w1.y) + lo16(w2.y) + lo16(w3.y);
        a[3] += hi16(w0.y) + hi16(w1.y) + hi16(w2.y) + hi16(w3.y);
        a[4] += lo16(w0.z) + lo16(w1.z) + lo16(w2.z) + lo16(w3.z);
        a[5] += hi16(w0.z) + hi16(w1.z) + hi16(w2.z) + hi16(w3.z);
        a[6] += lo16(w0.w) + lo16(w1.w) + lo16(w2.w) + lo16(w3.w);
        a[7] += hi16(w0.w) + hi16(w1.w) + hi16(w2.w) + hi16(w3.w);
    }
    for (; e < len; e++) {
        uint4 w = *(const uint4*)(base + (size_t)row[e] * 128);
        a[0] += lo16(w.x); a[1] += hi16(w.x);
        a[2] += lo16(w.y); a[3] += hi16(w.y);
        a[4] += lo16(w.z); a[5] += hi16(w.z);
        a[6] += lo16(w.w); a[7] += hi16(w.w);
    }
    if (selfAdd) {
        uint4 w = *(const uint4*)(base + (size_t)n * 128);
        a[0] += lo16(w.x); a[1] += hi16(w.x);
        a[2] += lo16(w.y); a[3] += hi16(w.y);
        a[4] += lo16(w.z); a[5] += hi16(w.z);
        a[6] += lo16(w.w); a[7] += hi16(w.w);
    }
    uint4 o;
    o.x = pack2(a[0] * scale, a[1] * scale);
    o.y = pack2(a[2] * scale, a[3] * scale);
    o.z = pack2(a[4] * scale, a[5] * scale);
    o.w = pack2(a[6] * scale, a[7] * scale);
    *(uint4*)(outb + (size_t)n * 128 + lane * 8) = o;
}

// ======== MFMA GEMM: out_bf16[nrows,128] = act(A_bf16 @ W + b) ========
template<bool RELU>
__global__ __launch_bounds__(256) void gemm_mfma(
    const ushort_t* __restrict__ A, const ushort_t* __restrict__ WT,
    const float* __restrict__ bias, ushort_t* __restrict__ outb, int nrows)
{
    __shared__ ushort_t Ws[128][136];
    int t = threadIdx.x;
    for (int j = t; j < 128 * 16; j += 256) {
        int n = j >> 4, kq = (j & 15) << 3;
        *(uint4*)&Ws[n][kq] = *(const uint4*)(WT + n * 128 + kq);
    }
    int wave = t >> 6, lane = t & 63;
    int m = lane & 15, quad = lane >> 4;
    int rowBase = blockIdx.x * 64 + wave * 16;
    int arow = rowBase + m; if (arow >= nrows) arow = 0;
    bf16x8 afr[4];
#pragma unroll
    for (int kt = 0; kt < 4; kt++) {
        U8 u; u.u = *(const uint4*)(A + (size_t)arow * 128 + kt * 32 + quad * 8);
        afr[kt] = u.v;
    }
    __syncthreads();
    f32x4 acc[8];
#pragma unroll
    for (int ct = 0; ct < 8; ct++) acc[ct] = (f32x4){0.f, 0.f, 0.f, 0.f};
#pragma unroll
    for (int ct = 0; ct < 8; ct++) {
#pragma unroll
        for (int kt = 0; kt < 4; kt++) {
            bf16x8 b = *(const bf16x8*)&Ws[ct * 16 + m][kt * 32 + quad * 8];
            acc[ct] = __builtin_amdgcn_mfma_f32_16x16x32_bf16(afr[kt], b, acc[ct], 0, 0, 0);
        }
    }
#pragma unroll
    for (int ct = 0; ct < 8; ct++) {
        int col = ct * 16 + m;
        float bb = bias[col];
#pragma unroll
        for (int r = 0; r < 4; r++) {
            int row = rowBase + quad * 4 + r;
            if (row < nrows) {
                float v = acc[ct][r] + bb;
                if (RELU) v = fmaxf(v, 0.f);
                outb[(size_t)row * 128 + col] = f2bf(v);
            }
        }
    }
}

// ======== final MFMA GEMM 128->47 + fused log_softmax (f32 out) ========
__global__ __launch_bounds__(256) void gemm47_lsm(
    const ushort_t* __restrict__ A, const ushort_t* __restrict__ WT,
    const float* __restrict__ bias, float* __restrict__ out, int nrows)
{
    __shared__ ushort_t Ws[48][136];
    int t = threadIdx.x;
    for (int j = t; j < 48 * 16; j += 256) {
        int n = j >> 4, kq = (j & 15) << 3;
        *(uint4*)&Ws[n][kq] = *(const uint4*)(WT + n * 128 + kq);
    }
    int wave = t >> 6, lane = t & 63;
    int m = lane & 15, quad = lane >> 4;
    int rowBase = blockIdx.x * 64 + wave * 16;
    int arow = rowBase + m; if (arow >= nrows) arow = 0;
    bf16x8 afr[4];
#pragma unroll
    for (int kt = 0; kt < 4; kt++) {
        U8 u; u.u = *(const uint4*)(A + (size_t)arow * 128 + kt * 32 + quad * 8);
        afr[kt] = u.v;
    }
    __syncthreads();
    f32x4 acc[3];
#pragma unroll
    for (int ct = 0; ct < 3; ct++) acc[ct] = (f32x4){0.f, 0.f, 0.f, 0.f};
#pragma unroll
    for (int ct = 0; ct < 3; ct++) {
#pragma unroll
        for (int kt = 0; kt < 4; kt++) {
            bf16x8 b = *(const bf16x8*)&Ws[ct * 16 + m][kt * 32 + quad * 8];
            acc[ct] = __builtin_amdgcn_mfma_f32_16x16x32_bf16(afr[kt], b, acc[ct], 0, 0, 0);
        }
    }
    int c0 = m, c1 = 16 + m, c2 = 32 + m;
    bool has2 = (c2 < 47);
    float b0 = bias[c0], b1 = bias[c1], b2 = has2 ? bias[c2] : 0.f;
#pragma unroll
    for (int r = 0; r < 4; r++) {
        int row = rowBase + quad * 4 + r;
        float v0 = acc[0][r] + b0;
        float v1 = acc[1][r] + b1;
        float v2 = has2 ? (acc[2][r] + b2) : -INFINITY;
        float mx = fmaxf(fmaxf(v0, v1), v2);
#pragma unroll
        for (int off = 8; off; off >>= 1) mx = fmaxf(mx, __shfl_xor(mx, off, 64));
        float s = __expf(v0 - mx) + __expf(v1 - mx) + (has2 ? __expf(v2 - mx) : 0.f);
#pragma unroll
        for (int off = 8; off; off >>= 1) s += __shfl_xor(s, off, 64);
        float lse = mx + __logf(s);
        if (row < nrows) {
            float* o = out + (size_t)row * 47;
            o[c0] = v0 - lse;
            o[c1] = v1 - lse;
            if (has2) o[c2] = v2 - lse;
        }
    }
}

extern "C" void kernel_launch(void* const* d_in, const int* in_sizes, int n_in,
                              void* d_out, int out_size, void* d_ws, size_t ws_size,
                              hipStream_t stream) {
    const float* x_in   = (const float*)d_in[0];    // fp32 [N,128]
    const int*   edge   = (const int*)d_in[1];      // [2,E]  row0=src row1=tgt
    const int*   ego    = (const int*)d_in[2];      // [2,EGO_E] row0=dst row1=src
    const float* W_ego0 = (const float*)d_in[3];
    const float* b_ego0 = (const float*)d_in[4];
    const float* W_gin0 = (const float*)d_in[5];
    const float* b_gin0 = (const float*)d_in[6];
    const float* W_ego1 = (const float*)d_in[7];
    const float* b_ego1 = (const float*)d_in[8];
    const float* W_gin1 = (const float*)d_in[9];
    const float* b_gin1 = (const float*)d_in[10];
    float* out = (float*)d_out;                     // fp32 [N,47]

    const int N     = in_sizes[0] / 128;
    const int E     = in_sizes[1] / 2;
    const int EGO_E = in_sizes[2] / 2;
    const float invN = 1.0f / (float)N;
    const int NB    = (N + 255) >> 8;               // 256-node bins

    // ---- workspace layout (~69 MB) ----
    const size_t NBELEM = (size_t)N * 128;
    ushort_t* Xb = (ushort_t*)d_ws;                 // bf16 [N,128]
    ushort_t* G  = Xb + NBELEM;                     // gather output (reused 4x)
    ushort_t* H  = G + NBELEM;                      // hidden (reused 3x)
    ushort_t* T0 = H + NBELEM;
    ushort_t* T1 = T0 + 16384;
    ushort_t* T2 = T1 + 16384;
    ushort_t* T3 = T2 + 16384;                      // [48][128]
    int* ip = (int*)(T3 + 6144);
    int* cnt_ego   = ip;             ip += NB * 256;
    int* rp_ego    = ip;             ip += NB * 256;
    int* rm_ego    = ip;             ip += NB * 256;
    int* cnt_edge  = ip;             ip += NB * 256;
    int* rp_edge   = ip;             ip += NB * 256;
    int* rm_edge   = ip;             ip += NB * 256;
    int* bincur    = ip;             ip += 512;     // [0..255]=ego, [256..511]=edge
    int2* stage_ego  = (int2*)ip;    ip += (size_t)NB * SCAP_EGO * 2;
    int*  pk_ego     = ip;           ip += (size_t)NB * SCAP_EGO;
    int2* stage_edge = (int2*)ip;    ip += (size_t)NB * SCAP_E * 2;
    int*  pk_edge    = ip;           ip += (size_t)NB * SCAP_E;

    const int gGemm   = (N + 63) / 64;
    const int gNode16 = (NB * 256) / 16;
    const int gBinE   = (EGO_E + 4095) / 4096;
    const int gBinF   = (E + 4095) / 4096;
    const int gCvt    = ((N * 128 / 8) + 255) / 256;

    // ---- prep + graph build (3 launches) ----
    prep<<<gCvt, 256, 0, stream>>>(x_in, Xb, N * 128 / 8,
                                   W_ego0, W_gin0, W_ego1, W_gin1,
                                   T0, T1, T2, T3, bincur);
    bin_edges2<<<gBinE + gBinF, 256, 0, stream>>>(
        ego, ego + EGO_E, EGO_E, gBinE, bincur, stage_ego, SCAP_EGO,
        edge + E, edge, E, bincur + 256, stage_edge, SCAP_E);
    build_csr2<<<2 * NB, 256, 0, stream>>>(
        bincur, stage_ego, SCAP_EGO, cnt_ego, rp_ego, pk_ego, rm_ego,
        bincur + 256, stage_edge, SCAP_E, cnt_edge, rp_edge, pk_edge, rm_edge, NB);

    // ---- network (8 launches) ----
    // layer 0: Ego conv
    gather_bf<<<gNode16, 256, 0, stream>>>(Xb, cnt_ego, rp_ego, pk_ego, rm_ego, G, N, invN, 0);
    gemm_mfma<true><<<gGemm, 256, 0, stream>>>(G, T0, b_ego0, H, N);           // H = h0
    // layer 0: GIN (self + aggr)
    gather_bf<<<gNode16, 256, 0, stream>>>(H, cnt_edge, rp_edge, pk_edge, rm_edge, G, N, 1.f, 1);
    gemm_mfma<true><<<gGemm, 256, 0, stream>>>(G, T1, b_gin0, H, N);           // H = h1
    // layer 1: Ego conv
    gather_bf<<<gNode16, 256, 0, stream>>>(H, cnt_ego, rp_ego, pk_ego, rm_ego, G, N, invN, 0);
    gemm_mfma<true><<<gGemm, 256, 0, stream>>>(G, T2, b_ego1, H, N);           // H = h2
    // layer 1: GIN + fused log_softmax
    gather_bf<<<gNode16, 256, 0, stream>>>(H, cnt_edge, rp_edge, pk_edge, rm_edge, G, N, 1.f, 1);
    gemm47_lsm<<<gGemm, 256, 0, stream>>>(G, T3, b_gin1, out, N);
}

// Round 16
// 308.101 us; speedup vs baseline: 1.0830x; 1.0830x over previous
//
#include <hip/hip_runtime.h>

#define SCAP_EGO 8192   // staging cap per 256-node bin (mean 6144)
#define SCAP_E   4096   // mean 3072

typedef unsigned short ushort_t;
typedef unsigned int uint_t;
typedef __attribute__((ext_vector_type(8))) short bf16x8;
typedef __attribute__((ext_vector_type(4))) float f32x4;

__device__ inline float lo16(uint_t u) { return __uint_as_float(u << 16); }
__device__ inline float hi16(uint_t u) { return __uint_as_float(u & 0xFFFF0000u); }
__device__ inline ushort_t f2bf(float f) {
    uint_t i = __float_as_uint(f);
    return (ushort_t)((i + 0x7FFFu + ((i >> 16) & 1u)) >> 16);
}
__device__ inline uint_t pack2(float a, float b) {
    return (uint_t)f2bf(a) | ((uint_t)f2bf(b) << 16);
}
union U8 { uint4 u; bf16x8 v; };

// ======== prep: x fp32->bf16, weights fp32->bf16 W^T, zero cursors ========
__global__ __launch_bounds__(256) void prep(
    const float* __restrict__ x, ushort_t* __restrict__ xb, int n8,
    const float* __restrict__ W0, const float* __restrict__ W1,
    const float* __restrict__ W2, const float* __restrict__ W3,
    ushort_t* __restrict__ T0, ushort_t* __restrict__ T1,
    ushort_t* __restrict__ T2, ushort_t* __restrict__ T3,
    int* __restrict__ z)
{
    int i = blockIdx.x * 256 + threadIdx.x;
    if (i < 128) ((int4*)z)[i] = make_int4(0, 0, 0, 0);
    if (i < n8) {
        const float4* p = (const float4*)(x + (size_t)i * 8);
        float4 a = p[0], b = p[1];
        uint4 o;
        o.x = pack2(a.x, a.y); o.y = pack2(a.z, a.w);
        o.z = pack2(b.x, b.y); o.w = pack2(b.z, b.w);
        *(uint4*)(xb + (size_t)i * 8) = o;
    }
    if (i < 49152) {
        int mi = i >> 14;
        int r = i & 16383;
        int n = r >> 7, k = r & 127;
        const float* W = mi == 0 ? W0 : (mi == 1 ? W1 : W2);
        ushort_t* T = mi == 0 ? T0 : (mi == 1 ? T1 : T2);
        T[n * 128 + k] = f2bf(W[k * 128 + n]);
    } else if (i < 49152 + 6144) {
        int r = i - 49152;
        int n = r >> 7, k = r & 127;
        T3[n * 128 + k] = (n < 47) ? f2bf(W3[k * 47 + n]) : (ushort_t)0;
    }
}

// ======== merged phase A: bin edges of BOTH graphs (block-range branch) ====
__global__ __launch_bounds__(256) void bin_edges2(
    const int* __restrict__ d1, const int* __restrict__ s1, int n1, int nb1,
    int* __restrict__ cur1, int2* __restrict__ st1, int scap1,
    const int* __restrict__ d2, const int* __restrict__ s2, int n2,
    int* __restrict__ cur2, int2* __restrict__ st2, int scap2)
{
    const int* dst; const int* src; int nE, scap; int* bincur; int2* stage; int bid;
    if (blockIdx.x < (uint_t)nb1) {
        dst = d1; src = s1; nE = n1; scap = scap1; bincur = cur1; stage = st1;
        bid = blockIdx.x;
    } else {
        dst = d2; src = s2; nE = n2; scap = scap2; bincur = cur2; stage = st2;
        bid = blockIdx.x - nb1;
    }
    __shared__ int bcnt[256];
    __shared__ int gbase[256];
    int t = threadIdx.x;
    bcnt[t] = 0;
    __syncthreads();
    int base = bid * 4096;
    int d[16], s[16], l[16];
#pragma unroll
    for (int i = 0; i < 16; i++) {
        int e = base + t + i * 256;
        if (e < nE) {
            d[i] = dst[e]; s[i] = src[e];
            l[i] = atomicAdd(&bcnt[d[i] >> 8], 1);
        } else d[i] = -1;
    }
    __syncthreads();
    if (bcnt[t]) gbase[t] = atomicAdd(&bincur[t], bcnt[t]);
    __syncthreads();
#pragma unroll
    for (int i = 0; i < 16; i++) {
        if (d[i] >= 0) {
            int b = d[i] >> 8;
            int slot = gbase[b] + l[i];
            if (slot < scap) stage[(size_t)b * scap + slot] = make_int2(d[i], s[i]);
        }
    }
}

// ======== merged phase B: per-bin counting sort -> packed CSR ========
// blocks [0,NB) = ego bins, [NB,2NB) = edge bins.
__global__ __launch_bounds__(256) void build_csr2(
    const int* __restrict__ cur1, const int2* __restrict__ st1, int scap1,
    int* __restrict__ cnt1, int* __restrict__ rp1, int* __restrict__ pk1,
    const int* __restrict__ cur2, const int2* __restrict__ st2, int scap2,
    int* __restrict__ cnt2, int* __restrict__ rp2, int* __restrict__ pk2,
    int NB)
{
    const int* bincur; const int2* stage; int scap;
    int* cnt; int* rowptr; int* packed; int b;
    if (blockIdx.x < (uint_t)NB) {
        bincur = cur1; stage = st1; scap = scap1;
        cnt = cnt1; rowptr = rp1; packed = pk1; b = blockIdx.x;
    } else {
        bincur = cur2; stage = st2; scap = scap2;
        cnt = cnt2; rowptr = rp2; packed = pk2; b = blockIdx.x - NB;
    }
    __shared__ int sc[256];
    __shared__ int wcur[256];
    int t = threadIdx.x;
    int m = bincur[b]; if (m > scap) m = scap;
    const int2* st = stage + (size_t)b * scap;
    sc[t] = 0;
    __syncthreads();
    for (int e = t; e < m; e += 256) atomicAdd(&sc[st[e].x & 255], 1);
    __syncthreads();
    int v = sc[t];
    __syncthreads();
    sc[t] = v;
    __syncthreads();
    for (int off = 1; off < 256; off <<= 1) {
        int y = (t >= off) ? sc[t - off] : 0;
        __syncthreads();
        sc[t] += y;
        __syncthreads();
    }
    int excl = sc[t] - v;
    cnt[b * 256 + t] = v;
    rowptr[b * 256 + t] = b * scap + excl;
    wcur[t] = excl;
    __syncthreads();
    int* pk = packed + (size_t)b * scap;
    for (int e = t; e < m; e += 256) {
        int2 p = st[e];
        int slot = atomicAdd(&wcur[p.x & 255], 1);
        pk[slot] = p.y;
    }
}

// ======== gather-sum: 16-lane group per node, uint4/lane, unroll x4 ========
// No LDS, ~40 VGPR -> high occupancy; 16 outstanding row-loads per wave64.
__global__ __launch_bounds__(256) void gather_bf(
    const ushort_t* __restrict__ x, const int* __restrict__ cnt,
    const int* __restrict__ rowptr, const int* __restrict__ packed,
    ushort_t* __restrict__ outb, int nNodes, float scale, int selfAdd)
{
    int g = threadIdx.x >> 4, lane = threadIdx.x & 15;
    int n = blockIdx.x * 16 + g;
    if (n >= nNodes) return;
    int len = cnt[n];
    const int* row = packed + rowptr[n];
    const ushort_t* base = x + lane * 8;
    float a[8];
#pragma unroll
    for (int m = 0; m < 8; m++) a[m] = 0.f;
    int e = 0;
    for (; e + 3 < len; e += 4) {
        int s0 = row[e], s1 = row[e + 1], s2 = row[e + 2], s3 = row[e + 3];
        uint4 w0 = *(const uint4*)(base + (size_t)s0 * 128);
        uint4 w1 = *(const uint4*)(base + (size_t)s1 * 128);
        uint4 w2 = *(const uint4*)(base + (size_t)s2 * 128);
        uint4 w3 = *(const uint4*)(base + (size_t)s3 * 128);
        a[0] += lo16(w0.x) + lo16(w1.x) + lo16(w2.x) + lo16(w3.x);
        a[1] += hi16(w0.x) + hi16(w1.x) + hi16(w2.x) + hi16(w3.x);
        a[2] += lo16(w0.y) + lo16(w1.y) + lo16(w2.y) + lo16(w3.y);
        a[3] += hi16(w0.y) + hi16(w1.y) + hi16(w2.y) + hi16(w3.y);
        a[4] += lo16(w0.z) + lo16(w1.z) + lo16(w2.z) + lo16(w3.z);
        a[5] += hi16(w0.z) + hi16(w1.z) + hi16(w2.z) + hi16(w3.z);
        a[6] += lo16(w0.w) + lo16(w1.w) + lo16(w2.w) + lo16(w3.w);
        a[7] += hi16(w0.w) + hi16(w1.w) + hi16(w2.w) + hi16(w3.w);
    }
    for (; e < len; e++) {
        uint4 w = *(const uint4*)(base + (size_t)row[e] * 128);
        a[0] += lo16(w.x); a[1] += hi16(w.x);
        a[2] += lo16(w.y); a[3] += hi16(w.y);
        a[4] += lo16(w.z); a[5] += hi16(w.z);
        a[6] += lo16(w.w); a[7] += hi16(w.w);
    }
    if (selfAdd) {
        uint4 w = *(const uint4*)(base + (size_t)n * 128);
        a[0] += lo16(w.x); a[1] += hi16(w.x);
        a[2] += lo16(w.y); a[3] += hi16(w.y);
        a[4] += lo16(w.z); a[5] += hi16(w.z);
        a[6] += lo16(w.w); a[7] += hi16(w.w);
    }
    uint4 o;
    o.x = pack2(a[0] * scale, a[1] * scale);
    o.y = pack2(a[2] * scale, a[3] * scale);
    o.z = pack2(a[4] * scale, a[5] * scale);
    o.w = pack2(a[6] * scale, a[7] * scale);
    *(uint4*)(outb + (size_t)n * 128 + lane * 8) = o;
}

// ======== MFMA GEMM: out_bf16[nrows,128] = act(A_bf16 @ W + b) ========
template<bool RELU>
__global__ __launch_bounds__(256) void gemm_mfma(
    const ushort_t* __restrict__ A, const ushort_t* __restrict__ WT,
    const float* __restrict__ bias, ushort_t* __restrict__ outb, int nrows)
{
    __shared__ ushort_t Ws[128][136];
    int t = threadIdx.x;
    for (int j = t; j < 128 * 16; j += 256) {
        int n = j >> 4, kq = (j & 15) << 3;
        *(uint4*)&Ws[n][kq] = *(const uint4*)(WT + n * 128 + kq);
    }
    int wave = t >> 6, lane = t & 63;
    int m = lane & 15, quad = lane >> 4;
    int rowBase = blockIdx.x * 64 + wave * 16;
    int arow = rowBase + m; if (arow >= nrows) arow = 0;
    bf16x8 afr[4];
#pragma unroll
    for (int kt = 0; kt < 4; kt++) {
        U8 u; u.u = *(const uint4*)(A + (size_t)arow * 128 + kt * 32 + quad * 8);
        afr[kt] = u.v;
    }
    __syncthreads();
    f32x4 acc[8];
#pragma unroll
    for (int ct = 0; ct < 8; ct++) acc[ct] = (f32x4){0.f, 0.f, 0.f, 0.f};
#pragma unroll
    for (int ct = 0; ct < 8; ct++) {
#pragma unroll
        for (int kt = 0; kt < 4; kt++) {
            bf16x8 b = *(const bf16x8*)&Ws[ct * 16 + m][kt * 32 + quad * 8];
            acc[ct] = __builtin_amdgcn_mfma_f32_16x16x32_bf16(afr[kt], b, acc[ct], 0, 0, 0);
        }
    }
#pragma unroll
    for (int ct = 0; ct < 8; ct++) {
        int col = ct * 16 + m;
        float bb = bias[col];
#pragma unroll
        for (int r = 0; r < 4; r++) {
            int row = rowBase + quad * 4 + r;
            if (row < nrows) {
                float v = acc[ct][r] + bb;
                if (RELU) v = fmaxf(v, 0.f);
                outb[(size_t)row * 128 + col] = f2bf(v);
            }
        }
    }
}

// ======== final MFMA GEMM 128->47 + fused log_softmax (f32 out) ========
__global__ __launch_bounds__(256) void gemm47_lsm(
    const ushort_t* __restrict__ A, const ushort_t* __restrict__ WT,
    const float* __restrict__ bias, float* __restrict__ out, int nrows)
{
    __shared__ ushort_t Ws[48][136];
    int t = threadIdx.x;
    for (int j = t; j < 48 * 16; j += 256) {
        int n = j >> 4, kq = (j & 15) << 3;
        *(uint4*)&Ws[n][kq] = *(const uint4*)(WT + n * 128 + kq);
    }
    int wave = t >> 6, lane = t & 63;
    int m = lane & 15, quad = lane >> 4;
    int rowBase = blockIdx.x * 64 + wave * 16;
    int arow = rowBase + m; if (arow >= nrows) arow = 0;
    bf16x8 afr[4];
#pragma unroll
    for (int kt = 0; kt < 4; kt++) {
        U8 u; u.u = *(const uint4*)(A + (size_t)arow * 128 + kt * 32 + quad * 8);
        afr[kt] = u.v;
    }
    __syncthreads();
    f32x4 acc[3];
#pragma unroll
    for (int ct = 0; ct < 3; ct++) acc[ct] = (f32x4){0.f, 0.f, 0.f, 0.f};
#pragma unroll
    for (int ct = 0; ct < 3; ct++) {
#pragma unroll
        for (int kt = 0; kt < 4; kt++) {
            bf16x8 b = *(const bf16x8*)&Ws[ct * 16 + m][kt * 32 + quad * 8];
            acc[ct] = __builtin_amdgcn_mfma_f32_16x16x32_bf16(afr[kt], b, acc[ct], 0, 0, 0);
        }
    }
    int c0 = m, c1 = 16 + m, c2 = 32 + m;
    bool has2 = (c2 < 47);
    float b0 = bias[c0], b1 = bias[c1], b2 = has2 ? bias[c2] : 0.f;
#pragma unroll
    for (int r = 0; r < 4; r++) {
        int row = rowBase + quad * 4 + r;
        float v0 = acc[0][r] + b0;
        float v1 = acc[1][r] + b1;
        float v2 = has2 ? (acc[2][r] + b2) : -INFINITY;
        float mx = fmaxf(fmaxf(v0, v1), v2);
#pragma unroll
        for (int off = 8; off; off >>= 1) mx = fmaxf(mx, __shfl_xor(mx, off, 64));
        float s = __expf(v0 - mx) + __expf(v1 - mx) + (has2 ? __expf(v2 - mx) : 0.f);
#pragma unroll
        for (int off = 8; off; off >>= 1) s += __shfl_xor(s, off, 64);
        float lse = mx + __logf(s);
        if (row < nrows) {
            float* o = out + (size_t)row * 47;
            o[c0] = v0 - lse;
            o[c1] = v1 - lse;
            if (has2) o[c2] = v2 - lse;
        }
    }
}

extern "C" void kernel_launch(void* const* d_in, const int* in_sizes, int n_in,
                              void* d_out, int out_size, void* d_ws, size_t ws_size,
                              hipStream_t stream) {
    const float* x_in   = (const float*)d_in[0];    // fp32 [N,128]
    const int*   edge   = (const int*)d_in[1];      // [2,E]  row0=src row1=tgt
    const int*   ego    = (const int*)d_in[2];      // [2,EGO_E] row0=dst row1=src
    const float* W_ego0 = (const float*)d_in[3];
    const float* b_ego0 = (const float*)d_in[4];
    const float* W_gin0 = (const float*)d_in[5];
    const float* b_gin0 = (const float*)d_in[6];
    const float* W_ego1 = (const float*)d_in[7];
    const float* b_ego1 = (const float*)d_in[8];
    const float* W_gin1 = (const float*)d_in[9];
    const float* b_gin1 = (const float*)d_in[10];
    float* out = (float*)d_out;                     // fp32 [N,47]

    const int N     = in_sizes[0] / 128;
    const int E     = in_sizes[1] / 2;
    const int EGO_E = in_sizes[2] / 2;
    const float invN = 1.0f / (float)N;
    const int NB    = (N + 255) >> 8;               // 256-node bins

    // ---- workspace layout (~69 MB) ----
    const size_t NBELEM = (size_t)N * 128;
    ushort_t* Xb = (ushort_t*)d_ws;                 // bf16 [N,128]
    ushort_t* G  = Xb + NBELEM;                     // gather output (reused 4x)
    ushort_t* H  = G + NBELEM;                      // hidden (reused 3x)
    ushort_t* T0 = H + NBELEM;
    ushort_t* T1 = T0 + 16384;
    ushort_t* T2 = T1 + 16384;
    ushort_t* T3 = T2 + 16384;                      // [48][128]
    int* ip = (int*)(T3 + 6144);
    int* cnt_ego   = ip;             ip += NB * 256;
    int* rp_ego    = ip;             ip += NB * 256;
    int* cnt_edge  = ip;             ip += NB * 256;
    int* rp_edge   = ip;             ip += NB * 256;
    int* bincur    = ip;             ip += 512;     // [0..255]=ego, [256..511]=edge
    int2* stage_ego  = (int2*)ip;    ip += (size_t)NB * SCAP_EGO * 2;
    int*  pk_ego     = ip;           ip += (size_t)NB * SCAP_EGO;
    int2* stage_edge = (int2*)ip;    ip += (size_t)NB * SCAP_E * 2;
    int*  pk_edge    = ip;           ip += (size_t)NB * SCAP_E;

    const int gGemm   = (N + 63) / 64;
    const int gNode16 = (N + 15) / 16;
    const int gBinE   = (EGO_E + 4095) / 4096;
    const int gBinF   = (E + 4095) / 4096;
    const int gCvt    = ((N * 128 / 8) + 255) / 256;

    // ---- prep + graph build (3 launches) ----
    prep<<<gCvt, 256, 0, stream>>>(x_in, Xb, N * 128 / 8,
                                   W_ego0, W_gin0, W_ego1, W_gin1,
                                   T0, T1, T2, T3, bincur);
    bin_edges2<<<gBinE + gBinF, 256, 0, stream>>>(
        ego, ego + EGO_E, EGO_E, gBinE, bincur, stage_ego, SCAP_EGO,
        edge + E, edge, E, bincur + 256, stage_edge, SCAP_E);
    build_csr2<<<2 * NB, 256, 0, stream>>>(
        bincur, stage_ego, SCAP_EGO, cnt_ego, rp_ego, pk_ego,
        bincur + 256, stage_edge, SCAP_E, cnt_edge, rp_edge, pk_edge, NB);

    // ---- network (8 launches) ----
    // layer 0: Ego conv
    gather_bf<<<gNode16, 256, 0, stream>>>(Xb, cnt_ego, rp_ego, pk_ego, G, N, invN, 0);
    gemm_mfma<true><<<gGemm, 256, 0, stream>>>(G, T0, b_ego0, H, N);           // H = h0
    // layer 0: GIN (self + aggr)
    gather_bf<<<gNode16, 256, 0, stream>>>(H, cnt_edge, rp_edge, pk_edge, G, N, 1.f, 1);
    gemm_mfma<true><<<gGemm, 256, 0, stream>>>(G, T1, b_gin0, H, N);           // H = h1
    // layer 1: Ego conv
    gather_bf<<<gNode16, 256, 0, stream>>>(H, cnt_ego, rp_ego, pk_ego, G, N, invN, 0);
    gemm_mfma<true><<<gGemm, 256, 0, stream>>>(G, T2, b_ego1, H, N);           // H = h2
    // layer 1: GIN + fused log_softmax
    gather_bf<<<gNode16, 256, 0, stream>>>(H, cnt_edge, rp_edge, pk_edge, G, N, 1.f, 1);
    gemm47_lsm<<<gGemm, 256, 0, stream>>>(G, T3, b_gin1, out, N);
}